// Round 1
// baseline (300.526 us; speedup 1.0000x reference)
//
#include <hip/hip_runtime.h>

// StealNMSLoss fused kernel for MI355X (gfx950).
//
// Math notes (verified against reference semantics):
//  - Composed Sobel-of-Sobel on a one-hot mask gives exact integer stencils /64:
//      gxx = [1,4,6,4,1]_h (x) [1,0,-2,0,1]_w / 64
//      gxy = [-1,-2,0,2,1]_h (x) [-1,-2,0,2,1]_w / 64
//      gyy = [1,0,-2,0,1]_h (x) [1,4,6,4,1]_w / 64
//    (kernel flipping is irrelevant: both first-order factors flip sign, cancelling)
//  - dir = f(round(atan(a)*5/pi)) collapses to threshold tests on |a| vs
//    tan(pi/10), tan(3pi/10); inputs are quantized to n/64 so boundaries are
//    never within fp32 rounding distance (margin ~1e-4 rel vs 1e-7 rounding).
//  - Only interior [2,H-2) x [2,W-2) contributes -> replicate padding irrelevant.
//  - dirs 1 and 3 use the identical offset set (anti-diagonal).

#define Bn 4
#define Cn 16
#define Hn 512
#define Wn 1024
#define TW 128           // output cols per block
#define TH 32            // output rows per block
#define LW 132           // TW + 4 halo
#define LH 36            // TH + 4 halo
#define NT 256           // 4 waves
#define CHALF 8          // classes per block (16 split over grid.z pairs)

#define EPSF 1.1920928955078125e-07f   // float32 eps
#define T1C 0.32491969623290623f       // tan(pi/10)
#define T2C 1.3763819204711735f        // tan(3pi/10)

typedef unsigned long long u64;
typedef unsigned int u32;

static __device__ __forceinline__ float fast_rcp(float x) {
#if __has_builtin(__builtin_amdgcn_rcpf)
  return __builtin_amdgcn_rcpf(x);   // v_rcp_f32, ~1 ulp: fine at 2% tolerance
#else
  return 1.0f / x;
#endif
}

__global__ __launch_bounds__(NT)
void steal_nms_kernel(const float* __restrict__ pred,
                      const int* __restrict__ labels,
                      float* __restrict__ out)
{
  __shared__ unsigned char labt[LH][LW];  // label tile (bytes), reused all classes
  __shared__ float ext[LH][LW];           // exp(pred) tile, per class
  __shared__ float wsum[NT/64];

  const int w0 = blockIdx.x * TW;
  const int h0 = blockIdx.y * TH;
  const int bz = blockIdx.z;
  const int b  = bz >> 1;
  const int c0 = (bz & 1) * CHALF;
  const int tid = threadIdx.x;

  // ---- fill label tile (u32-packed writes; clamped coords only feed
  //      never-summed border outputs) ----
  for (int i = tid; i < LH * (LW/4); i += NT) {
    int row  = i / (LW/4);
    int col4 = (i - row*(LW/4)) * 4;
    int gh = h0 - 2 + row; gh = min(max(gh, 0), Hn-1);
    const int* lrow = labels + gh * Wn;
    u32 v = 0;
    #pragma unroll
    for (int k = 0; k < 4; ++k) {
      int gw = w0 - 2 + col4 + k; gw = min(max(gw, 0), Wn-1);
      v |= (u32)(lrow[gw] & 0xff) << (8*k);
    }
    *(u32*)&labt[row][col4] = v;
  }
  __syncthreads();

  const int lane = tid & 63;
  const int wq   = tid >> 6;     // wave id: rows [8*wq, 8*wq+8)
  const int hr0  = wq * 8;

  // ---- cache per-lane 6-byte label windows for its 12 tile rows ----
  // lane owns output cols {2*lane, 2*lane+1}; stencil cols span bytes
  // [2*lane, 2*lane+5] of each label row.
  u64 wv[12];
  {
    const int byte0 = 2*lane;
    const int j0 = byte0 >> 2;
    const int sh = (byte0 & 3) * 8;
    #pragma unroll
    for (int r = 0; r < 12; ++r) {
      const u32* rowp = (const u32*)&labt[hr0 + r][0];
      u64 lo = rowp[j0];
      u64 hi = rowp[j0 + 1];
      wv[r] = ((hi << 32) | lo) >> sh;   // bytes 0..5 = window cols -2..+3
    }
  }

  const int gw0 = w0 + 2*lane;
  const bool wvalid0 = (gw0     >= 2) && (gw0     < Wn-2);
  const bool wvalid1 = (gw0 + 1 >= 2) && (gw0 + 1 < Wn-2);

  float acc = 0.f;

  #pragma unroll 1
  for (int cc = 0; cc < CHALF; ++cc) {
    const int c = c0 + cc;
    __syncthreads();   // protect previous class's ext readers

    // ---- fill exp tile for class c (float2-coalesced) ----
    {
      const float* plane = pred + (size_t)(b*Cn + c) * (size_t)(Hn*Wn);
      for (int i = tid; i < LH*(LW/2); i += NT) {
        int row = i / (LW/2);
        int col = (i - row*(LW/2)) * 2;
        int gh = h0 - 2 + row; gh = min(max(gh, 0), Hn-1);
        int ga = w0 - 2 + col;
        int gb = ga + 1;
        ga = min(max(ga, 0), Wn-1);
        gb = min(max(gb, 0), Wn-1);
        const float* prow = plane + gh*Wn;
        float e0 = __expf(prow[ga]);
        float e1 = __expf(prow[gb]);
        *(float2*)&ext[row][col] = make_float2(e0, e1);
      }
    }
    __syncthreads();

    // ---- per-class 0/1 mask bytes via SWAR zero-detect ----
    // window bytes are <=15, so (0x80 - x) & 0x80 flags x==0 exactly.
    u64 mm[12];
    {
      const u64 crep = 0x0101010101010101ULL * (u32)c;
      const u64 m80  = 0x8080808080808080ULL;
      #pragma unroll
      for (int r = 0; r < 12; ++r) {
        u64 x = wv[r] ^ crep;
        mm[r] = ((m80 - x) & m80) >> 7;
      }
    }

    // ---- rolling 4-row exp register window, prefill 3 rows ----
    float exr[4][5];
    const int fb = 2*lane;
    #pragma unroll
    for (int r = 0; r < 3; ++r) {
      float2 p0 = *(const float2*)&ext[hr0 + r][fb];
      float2 p1 = *(const float2*)&ext[hr0 + r][fb + 2];
      exr[r][0] = p0.x; exr[r][1] = p0.y;
      exr[r][2] = p1.x; exr[r][3] = p1.y;
      exr[r][4] = ext[hr0 + r][fb + 4];
    }

    #pragma unroll
    for (int i = 0; i < 8; ++i) {
      { // load newest row (array row hr0+i+3) into rotating slot
        const int rn = (i + 3) & 3;
        float2 p0 = *(const float2*)&ext[hr0 + i + 3][fb];
        float2 p1 = *(const float2*)&ext[hr0 + i + 3][fb + 2];
        exr[rn][0] = p0.x; exr[rn][1] = p0.y;
        exr[rn][2] = p1.x; exr[rn][3] = p1.y;
        exr[rn][4] = ext[hr0 + i + 3][fb + 4];
      }

      // ---- packed-byte vertical sums (per window col, all 6 cols at once) ----
      // A  = rows . [1,4,6,4,1]            in [0,16]
      // Bb = rows . [-1,-2,0,2,1] + 4      in [1,7]
      // Cb = rows . [1,0,-2,0,1]  + 4      in [2,6]
      u64 m0 = mm[i], m1 = mm[i+1], m2 = mm[i+2], m3 = mm[i+3], m4 = mm[i+4];
      u64 s13 = m1 + m3;
      u64 A  = m0 + m4 + (s13 << 2) + (m2 << 2) + (m2 << 1);
      u64 Bb = 0x0404040404040404ULL + (m3 << 1) + m4 - m0 - (m1 << 1);
      u64 Cb = 0x0404040404040404ULL + m0 + m4 - (m2 << 1);

      #define BY(x,k) ((int)((u32)((x) >> (8*(k))) & 0xffu))
      int A0=BY(A,0), A1=BY(A,1), A2=BY(A,2), A3=BY(A,3), A4=BY(A,4), A5=BY(A,5);
      int B0=BY(Bb,0), B1=BY(Bb,1), B2=BY(Bb,2), B3=BY(Bb,3), B4=BY(Bb,4), B5=BY(Bb,5);
      int C0=BY(Cb,0), C1=BY(Cb,1), C2=BY(Cb,2), C3=BY(Cb,3), C4=BY(Cb,4), C5=BY(Cb,5);
      #undef BY

      // horizontal dots (64*g values, exact ints; biases cancel where sum==0)
      int gxx0 = A0 + A4 - 2*A2;
      int gxx1 = A1 + A5 - 2*A3;
      int gxyS0 = 2*(B3 - B1) + (B4 - B0);       // sign(gxy) only
      int gxyS1 = 2*(B4 - B2) + (B5 - B1);
      int gyy0 = C0 + C4 + 4*(C1 + C3) + 6*C2 - 64;
      int gyy1 = C1 + C5 + 4*(C2 + C4) + 6*C3 - 64;

      // ---- atan-free direction classification ----
      float den0 = fmaf((float)gxx0, 0.015625f, EPSF);   // gxx/64 + eps, exact
      float den1 = fmaf((float)gxx1, 0.015625f, EPSF);
      float gy0 = (float)gyy0 * 0.015625f;
      float gy1 = (float)gyy1 * 0.015625f;
      float num0 = (gxyS0 > 0) ? -gy0 : gy0;             // s = sign(-gxy+eps)
      float num1 = (gxyS1 > 0) ? -gy1 : gy1;
      float an0 = fabsf(gy0), an1 = fabsf(gy1);
      float ad0 = fabsf(den0), ad1 = fabsf(den1);
      int rb0 = (int)(an0 >= T1C*ad0) + (int)(an0 >= T2C*ad0);
      int rb1 = (int)(an1 >= T1C*ad1) + (int)(an1 >= T2C*ad1);
      bool ng0 = ((__float_as_int(num0) ^ __float_as_int(den0)) < 0);
      bool ng1 = ((__float_as_int(num1) ^ __float_as_int(den1)) < 0);
      // r=+1->1, +2->2, 0->0, -1->0, -2->3
      int dir0 = ng0 ? ((rb0 == 2) ? 3 : 0) : rb0;
      int dir1 = ng1 ? ((rb1 == 2) ? 3 : 0) : rb1;

      // window rows: r0 = gh-2 .. r3 = gh+1 ; cols: [k .. k+4] = gw-2 .. gw+2
      const float* r0 = exr[(i+0)&3];
      const float* r1 = exr[(i+1)&3];
      const float* r2 = exr[(i+2)&3];
      const float* r3 = exr[(i+3)&3];

      float t12 = r2[1] + r2[2];
      float D0a = t12 + r2[0] + r2[3];                    // horizontal
      float D0b = t12 + r2[3] + r2[4];
      float D2a = (r0[2] + r1[2]) + (r2[2] + r3[2]);      // vertical
      float D2b = (r0[3] + r1[3]) + (r2[3] + r3[3]);
      float Dda = (r0[3] + r1[2]) + (r2[1] + r3[0]);      // anti-diagonal (dir 1&3)
      float Ddb = (r0[4] + r1[3]) + (r2[2] + r3[1]);

      float dena = (dir0 == 0) ? D0a : ((dir0 == 2) ? D2a : Dda);
      float denb = (dir1 == 0) ? D0b : ((dir1 == 2) ? D2b : Ddb);

      const int gh = h0 + hr0 + i;
      const bool hv = (gh >= 2) && (gh < Hn-2);
      float na = (hv && wvalid0) ? r2[2] : 0.f;
      float nb = (hv && wvalid1) ? r2[3] : 0.f;
      acc += na * fast_rcp(dena);
      acc += nb * fast_rcp(denb);
    }
  }

  // ---- reduce: wave shuffle -> LDS -> one atomic per block ----
  #pragma unroll
  for (int off = 32; off > 0; off >>= 1)
    acc += __shfl_down(acc, off);
  if (lane == 0) wsum[wq] = acc;
  __syncthreads();
  if (tid == 0) {
    float s = 0.f;
    #pragma unroll
    for (int q = 0; q < NT/64; ++q) s += wsum[q];
    atomicAdd(out, s);
  }
}

extern "C" void kernel_launch(void* const* d_in, const int* in_sizes, int n_in,
                              void* d_out, int out_size, void* d_ws, size_t ws_size,
                              hipStream_t stream) {
  (void)in_sizes; (void)n_in; (void)d_ws; (void)ws_size; (void)out_size;
  const float* pred   = (const float*)d_in[0];
  const int*   labels = (const int*)d_in[1];
  float* out = (float*)d_out;

  // d_out is re-poisoned before every timed launch
  hipMemsetAsync(out, 0, sizeof(float), stream);

  dim3 grid(Wn/TW, Hn/TH, Bn*2);   // 8 x 16 x 8 = 1024 blocks, 8 classes each
  steal_nms_kernel<<<grid, NT, 0, stream>>>(pred, labels, out);
}